// Round 1
// baseline (434.082 us; speedup 1.0000x reference)
//
#include <hip/hip_runtime.h>

#define NPOLY 969
#define KPAD  1024

typedef _Float16 half8  __attribute__((ext_vector_type(8)));
typedef float    float4v __attribute__((ext_vector_type(4)));

// Monomial tables matching TaylorMap._poly ordering:
// k=0: 1 ; k=1..16: x_i ; k=17..152: x_i*x_a (a<=i, i outer) ;
// k=153..968: x_i*x_a*x_b (b<=a<=i, i outer, then a, then b); 969..1023: pad 0.
struct Tbl { int d[KPAD]; int i[KPAD]; int a[KPAD]; int b[KPAD]; };
static constexpr Tbl mk_tbl() {
  Tbl t{};
  int k = 0;
  t.d[k] = 0; t.i[k] = 0; t.a[k] = 0; t.b[k] = 0; ++k;
  for (int i = 0; i < 16; ++i) { t.d[k] = 1; t.i[k] = i; t.a[k] = 0; t.b[k] = 0; ++k; }
  for (int i = 0; i < 16; ++i)
    for (int a = 0; a <= i; ++a) { t.d[k] = 2; t.i[k] = i; t.a[k] = a; t.b[k] = 0; ++k; }
  for (int i = 0; i < 16; ++i)
    for (int a = 0; a <= i; ++a)
      for (int b = 0; b <= a; ++b) { t.d[k] = 3; t.i[k] = i; t.a[k] = a; t.b[k] = b; ++k; }
  for (; k < KPAD; ++k) { t.d[k] = 4; t.i[k] = 0; t.a[k] = 0; t.b[k] = 0; }
  return t;
}
static constexpr Tbl TBL = mk_tbl();

// Block = 256 threads = 4 waves; each wave owns 64 rows (lane == row).
// K padded to 1024 = 8 chunks x 128 feats (4 MFMA K-steps of 32).
// Per-wave private 16 KB LDS feature buffer, XOR-swizzled 16B granules.
__global__ __launch_bounds__(256, 2)
void taylor_fwd(const float* __restrict__ X, const float* __restrict__ W,
                float* __restrict__ O) {
  extern __shared__ __align__(16) char smem[];
  const int tid  = threadIdx.x;
  const int lane = tid & 63;
  const int wv   = tid >> 6;
  const int n    = lane & 15;   // MFMA m/n index
  const int q    = lane >> 4;   // MFMA quad (k-slice)

  // ---- Phase 1: stage W (fp32, 62016 B) into LDS, coalesced float4 ----
  {
    const float4v* wg  = (const float4v*)W;
    float4v*       wl4 = (float4v*)smem;
    #pragma unroll
    for (int it = 0; it < 16; ++it) {
      int idx = tid + it * 256;
      if (idx < (NPOLY * 16) / 4) wl4[idx] = wg[idx];
    }
  }
  __syncthreads();

  // ---- Phase 2: extract B fragments into registers (128 VGPRs).
  // B[k][n], lane holds k = s*32 + q*8 + j, half j. Residual +x folded in:
  // W'[k][n] += (k == n+1).
  half8 bf[32];
  {
    const float* wl = (const float*)smem;
    #pragma unroll
    for (int s = 0; s < 32; ++s) {
      half8 hv;
      #pragma unroll
      for (int j = 0; j < 8; ++j) {
        const int k = s * 32 + q * 8 + j;
        float v = (k < NPOLY) ? wl[k * 16 + n] : 0.0f;
        if (k == n + 1) v += 1.0f;   // identity: out = x + poly@W
        hv[j] = (_Float16)v;
      }
      bf[s] = hv;
    }
  }
  __syncthreads();   // all waves done reading W region; reuse it for features

  // ---- Load my row of x (64 B contiguous per lane) ----
  const int rb = blockIdx.x * 256 + wv * 64;   // this wave's row base
  float xr[16];
  {
    const float4v* xp = (const float4v*)(X + (size_t)(rb + lane) * 16);
    float4v v0 = xp[0], v1 = xp[1], v2 = xp[2], v3 = xp[3];
    xr[0] = v0[0]; xr[1] = v0[1]; xr[2]  = v0[2]; xr[3]  = v0[3];
    xr[4] = v1[0]; xr[5] = v1[1]; xr[6]  = v1[2]; xr[7]  = v1[3];
    xr[8] = v2[0]; xr[9] = v2[1]; xr[10] = v2[2]; xr[11] = v2[3];
    xr[12] = v3[0]; xr[13] = v3[1]; xr[14] = v3[2]; xr[15] = v3[3];
  }

  _Float16* feat = (_Float16*)(smem + wv * 16384);   // per-wave 16 KB

  float4v acc[4];
  #pragma unroll
  for (int t = 0; t < 4; ++t) acc[t] = (float4v){0.f, 0.f, 0.f, 0.f};

  #pragma unroll
  for (int c = 0; c < 8; ++c) {
    // ---- stage 128 features of my row (uniform code, constexpr indices) ----
    #pragma unroll
    for (int g = 0; g < 16; ++g) {
      half8 hv;
      #pragma unroll
      for (int u = 0; u < 8; ++u) {
        const int k = c * 128 + g * 8 + u;
        float v;
        if      (TBL.d[k] == 0) v = 1.0f;
        else if (TBL.d[k] == 1) v = xr[TBL.i[k]];
        else if (TBL.d[k] == 2) v = xr[TBL.i[k]] * xr[TBL.a[k]];
        else if (TBL.d[k] == 3) v = xr[TBL.i[k]] * (xr[TBL.a[k]] * xr[TBL.b[k]]);
        else                    v = 0.0f;
        hv[u] = (_Float16)v;
      }
      const int gp = g ^ (lane & 7);                       // XOR granule swizzle
      *(half8*)(feat + lane * 128 + gp * 8) = hv;          // ds_write_b128
    }
    // wave-private producer->consumer: drain LDS writes (all 64 lanes)
    __asm__ volatile("s_waitcnt lgkmcnt(0)" ::: "memory");

    // ---- consume: 4 K-steps x 4 m-tiles of 16 rows ----
    #pragma unroll
    for (int s = 0; s < 4; ++s) {
      #pragma unroll
      for (int t = 0; t < 4; ++t) {
        const int row = t * 16 + n;                        // A: m = lane&15
        const int gp  = (s * 4 + q) ^ (n & 7);             // same swizzle
        half8 af = *(const half8*)(feat + row * 128 + gp * 8);  // ds_read_b128
        acc[t] = __builtin_amdgcn_mfma_f32_16x16x32_f16(af, bf[c * 4 + s], acc[t], 0, 0, 0);
      }
    }
    // ensure chunk-c reads retired before chunk-c+1 overwrites the buffer
    __asm__ volatile("s_waitcnt lgkmcnt(0)" ::: "memory");
  }

  // ---- Epilogue: C/D layout col = lane&15, row = q*4 + reg ----
  #pragma unroll
  for (int t = 0; t < 4; ++t) {
    #pragma unroll
    for (int r = 0; r < 4; ++r) {
      const int row = rb + t * 16 + q * 4 + r;
      O[(size_t)row * 16 + n] = acc[t][r];
    }
  }
}

extern "C" void kernel_launch(void* const* d_in, const int* in_sizes, int n_in,
                              void* d_out, int out_size, void* d_ws, size_t ws_size,
                              hipStream_t stream) {
  const float* X = (const float*)d_in[0];
  const float* W = (const float*)d_in[1];
  float*       O = (float*)d_out;
  const int batch = in_sizes[0] / 16;    // 262144
  const int grid  = batch / 256;         // 1024 blocks, 256 rows each
  taylor_fwd<<<grid, 256, 65536, stream>>>(X, W, O);
}

// Round 2
// 99.007 us; speedup vs baseline: 4.3844x; 4.3844x over previous
//
#include <hip/hip_runtime.h>

#define NPOLY  969
#define KPAD   1024
#define NCHUNK 16        // 16 chunks x 64 features

typedef _Float16 half8   __attribute__((ext_vector_type(8)));
typedef float    float4v __attribute__((ext_vector_type(4)));

// Monomial table, TaylorMap._poly ordering:
// k=0: 1 ; k=1..16: x_i ; k=17..152: x_i*x_a (a<=i) ; k=153..968: x_i*x_a*x_b (b<=a<=i).
struct Tbl { short d[KPAD]; short i[KPAD]; short a[KPAD]; short b[KPAD]; };
static constexpr Tbl mk_tbl() {
  Tbl t{};
  int k = 0;
  t.d[k] = 0; ++k;
  for (int i = 0; i < 16; ++i) { t.d[k] = 1; t.i[k] = (short)i; ++k; }
  for (int i = 0; i < 16; ++i)
    for (int a = 0; a <= i; ++a) { t.d[k] = 2; t.i[k] = (short)i; t.a[k] = (short)a; ++k; }
  for (int i = 0; i < 16; ++i)
    for (int a = 0; a <= i; ++a)
      for (int b = 0; b <= a; ++b) {
        t.d[k] = 3; t.i[k] = (short)i; t.a[k] = (short)a; t.b[k] = (short)b; ++k;
      }
  for (; k < KPAD; ++k) t.d[k] = 4;
  return t;
}
static constexpr Tbl TBL = mk_tbl();

// K is a template parameter -> all xr[] indices are C++ constant expressions.
// No dynamic register indexing can survive to codegen.
template<int K>
__device__ __forceinline__ float monomial(const float (&xr)[16]) {
  if constexpr (TBL.d[K] == 0)      return 1.0f;
  else if constexpr (TBL.d[K] == 1) return xr[TBL.i[K]];
  else if constexpr (TBL.d[K] == 2) return xr[TBL.i[K]] * xr[TBL.a[K]];
  else if constexpr (TBL.d[K] == 3) return xr[TBL.i[K]] * (xr[TBL.a[K]] * xr[TBL.b[K]]);
  else                              return 0.0f;
}

// Write one 8-feature granule (16 B) of this lane's row, XOR-swizzled.
template<int C, int G>
__device__ __forceinline__ void produce(const float (&xr)[16], _Float16* featrow, int lane) {
  half8 hv;
  hv[0] = (_Float16)monomial<C * 64 + G * 8 + 0>(xr);
  hv[1] = (_Float16)monomial<C * 64 + G * 8 + 1>(xr);
  hv[2] = (_Float16)monomial<C * 64 + G * 8 + 2>(xr);
  hv[3] = (_Float16)monomial<C * 64 + G * 8 + 3>(xr);
  hv[4] = (_Float16)monomial<C * 64 + G * 8 + 4>(xr);
  hv[5] = (_Float16)monomial<C * 64 + G * 8 + 5>(xr);
  hv[6] = (_Float16)monomial<C * 64 + G * 8 + 6>(xr);
  hv[7] = (_Float16)monomial<C * 64 + G * 8 + 7>(xr);
  const int gp = G ^ (lane & 7);
  *(half8*)(featrow + gp * 8) = hv;                      // ds_write_b128
}

template<int C, int G>
__device__ __forceinline__ void produce_all(const float (&xr)[16], _Float16* featrow, int lane) {
  if constexpr (G < 8) {
    produce<C, G>(xr, featrow, lane);
    produce_all<C, G + 1>(xr, featrow, lane);
  }
}

template<int C>
__device__ __forceinline__ void chunks(const float (&xr)[16], _Float16* feat,
                                       const _Float16* wfrag, int lane, int n, int q,
                                       float4v (&acc)[4]) {
  if constexpr (C < NCHUNK) {
    // ---- produce 64 features of my row into the per-wave LDS buffer ----
    produce_all<C, 0>(xr, feat + lane * 64, lane);
    __asm__ volatile("s_waitcnt lgkmcnt(0)" ::: "memory");

    // ---- consume: 2 K-steps of 32, 4 m-tiles of 16 rows ----
    #pragma unroll
    for (int s = 0; s < 2; ++s) {
      // B fragment: k = (C*2+s)*32 + q*8 + j, column n  (granule (C*8+s*4+q), n)
      half8 bf = *(const half8*)(wfrag + ((C * 8 + s * 4 + q) * 16 + n) * 8);
      #pragma unroll
      for (int t = 0; t < 4; ++t) {
        const int row = t * 16 + n;                       // A: m = lane&15
        const int gp  = (s * 4 + q) ^ (row & 7);
        half8 af = *(const half8*)(feat + row * 64 + gp * 8);   // ds_read_b128
        acc[t] = __builtin_amdgcn_mfma_f32_16x16x32_f16(af, bf, acc[t], 0, 0, 0);
      }
    }
    // same-wave DS ordering would protect the next chunk's overwrite, but the
    // drain is nearly free here (reads already consumed by MFMA)
    __asm__ volatile("s_waitcnt lgkmcnt(0)" ::: "memory");

    chunks<C + 1>(xr, feat, wfrag, lane, n, q, acc);
  }
}

// Block = 256 threads = 4 waves; each wave owns 64 rows (lane == row producer).
// LDS: [0,32K) transposed half W-fragments; [32K,64K) 8 KB feature buf per wave.
__global__ __launch_bounds__(256, 2)
void taylor_fwd(const float* __restrict__ X, const float* __restrict__ W,
                float* __restrict__ O) {
  extern __shared__ __align__(16) char smem[];
  _Float16* wfrag = (_Float16*)smem;
  const int tid  = threadIdx.x;
  const int lane = tid & 63;
  const int wv   = tid >> 6;
  const int n    = lane & 15;     // MFMA m/n index
  const int q    = lane >> 4;     // MFMA quad (k-slice)

  // ---- Phase 1: build half-precision transposed W fragments in LDS.
  // Entry e=(g,n0): 8 halfs = W[g*8+j][n0] (+1 on identity k==n0+1), 2048 entries.
  {
    #pragma unroll
    for (int pass = 0; pass < 8; ++pass) {
      const int e  = pass * 256 + tid;
      const int g  = e >> 4;
      const int n0 = e & 15;
      half8 hv;
      #pragma unroll
      for (int j = 0; j < 8; ++j) {
        const int k = g * 8 + j;
        float v = (k < NPOLY) ? W[k * 16 + n0] : 0.0f;
        if (k == n0 + 1) v += 1.0f;      // fold residual: out = x + poly@W
        hv[j] = (_Float16)v;
      }
      *(half8*)(wfrag + e * 8) = hv;
    }
  }
  __syncthreads();

  // ---- Load my row of x (64 B contiguous per lane) ----
  const int rb = blockIdx.x * 256 + wv * 64;
  float xr[16];
  {
    const float4v* xp = (const float4v*)(X + (size_t)(rb + lane) * 16);
    float4v v0 = xp[0], v1 = xp[1], v2 = xp[2], v3 = xp[3];
    xr[0]  = v0[0]; xr[1]  = v0[1]; xr[2]  = v0[2]; xr[3]  = v0[3];
    xr[4]  = v1[0]; xr[5]  = v1[1]; xr[6]  = v1[2]; xr[7]  = v1[3];
    xr[8]  = v2[0]; xr[9]  = v2[1]; xr[10] = v2[2]; xr[11] = v2[3];
    xr[12] = v3[0]; xr[13] = v3[1]; xr[14] = v3[2]; xr[15] = v3[3];
  }

  _Float16* feat = (_Float16*)(smem + 32768 + wv * 8192);  // 64 rows x 128 B

  float4v acc[4];
  #pragma unroll
  for (int t = 0; t < 4; ++t) acc[t] = (float4v){0.f, 0.f, 0.f, 0.f};

  chunks<0>(xr, feat, wfrag, lane, n, q, acc);

  // ---- Epilogue: C/D layout col = lane&15, row = q*4 + reg ----
  #pragma unroll
  for (int t = 0; t < 4; ++t) {
    #pragma unroll
    for (int r = 0; r < 4; ++r) {
      const int row = rb + t * 16 + q * 4 + r;
      O[(size_t)row * 16 + n] = acc[t][r];
    }
  }
}

extern "C" void kernel_launch(void* const* d_in, const int* in_sizes, int n_in,
                              void* d_out, int out_size, void* d_ws, size_t ws_size,
                              hipStream_t stream) {
  const float* X = (const float*)d_in[0];
  const float* W = (const float*)d_in[1];
  float*       O = (float*)d_out;
  const int batch = in_sizes[0] / 16;    // 262144
  const int grid  = batch / 256;         // 1024 blocks x 256 rows
  taylor_fwd<<<grid, 256, 65536, stream>>>(X, W, O);
}

// Round 4
// 90.536 us; speedup vs baseline: 4.7946x; 1.0936x over previous
//
#include <hip/hip_runtime.h>

#define NSTEP 39                 // K = 39*32 = 1248 slots
#define NCOL  (NSTEP * 8)        // 312 feature columns (8 per K-step), 4 q-slots each

typedef _Float16 half8   __attribute__((ext_vector_type(8)));
typedef __fp16   f16x2   __attribute__((ext_vector_type(2)));
typedef __fp16   f16x4   __attribute__((ext_vector_type(4)));
typedef __fp16   f16x8   __attribute__((ext_vector_type(8)));
typedef float    float4v __attribute__((ext_vector_type(4)));

// Column table. Each column c holds 4 features (q = 0..3):
//   mode 3: x_a * x_b * x_{o+q}   (deg-3; valid iff o+q <= 15)
//   mode 2: x_a * x_{o+q}         (deg-2; valid iff o+q <= a)
//   mode 1: x_{o+q}               (deg-1; always valid; carries +identity)
//   mode 4: 1.0                   (deg-0; valid iff q == 0)
//   mode 0: pad (feature 0, W row 0)
// Invalid slots are zeroed on the W side; the A side computes a finite
// garbage value (clamped w index) that multiplies W=0.
struct Cols { short mode[NCOL]; short a[NCOL]; short b[NCOL]; short o[NCOL]; };
static constexpr Cols mk_cols() {
  Cols c{};
  int k = 0;
  for (int o = 0; o < 16; o += 4) { c.mode[k] = 1; c.o[k] = (short)o; ++k; }   // deg-1: 4 cols
  c.mode[k] = 4; ++k;                                                          // deg-0: 1 col
  for (int a = 0; a < 16; ++a)                                                 // deg-2: 40 cols
    for (int o = 0; o <= a; o += 4) { c.mode[k] = 2; c.a[k] = (short)a; c.o[k] = (short)o; ++k; }
  for (int a = 0; a < 16; ++a)                                                 // deg-3: 260 cols
    for (int b = 0; b <= a; ++b)
      for (int o = a; o < 16; o += 4) {
        c.mode[k] = 3; c.a[k] = (short)a; c.b[k] = (short)b; c.o[k] = (short)o; ++k;
      }
  for (; k < NCOL; ++k) c.mode[k] = 0;                                         // 7 pad cols
  return c;
}
static constexpr Cols COLS = mk_cols();

// ---- Pre-kernel: build f16 W fragments (with permutation + zeroing + identity
// fold) into d_ws. Entry e = (step, q, n): 8 halfs = B[k=step*32+q*8+j][n].
__global__ void build_wfrag(const float* __restrict__ W, _Float16* __restrict__ Wp) {
  const int e = blockIdx.x * 256 + threadIdx.x;
  if (e >= NSTEP * 64) return;
  const int step = e >> 6;
  const int q    = (e >> 4) & 3;
  const int n    = e & 15;
  half8 hv;
  #pragma unroll
  for (int j = 0; j < 8; ++j) {
    const int c = step * 8 + j;
    const int mode = COLS.mode[c], a = COLS.a[c], b = COLS.b[c], o = COLS.o[c];
    float v = 0.0f;
    if (mode == 3) {
      const int i = o + q;
      if (i < 16) v = W[(153 + i * (i + 1) * (i + 2) / 6 + a * (a + 1) / 2 + b) * 16 + n];
    } else if (mode == 2) {
      const int bb = o + q;
      if (bb <= a) v = W[(17 + a * (a + 1) / 2 + bb) * 16 + n];
    } else if (mode == 1) {
      const int i = o + q;
      v = W[(1 + i) * 16 + n];
      if (i == n) v += 1.0f;               // fold residual: out = x + poly@W
    } else if (mode == 4) {
      if (q == 0) v = W[n];
    }
    hv[j] = (_Float16)v;
  }
  *(half8*)(Wp + e * 8) = hv;
}

// Feature value for column C (wave-uniform; q-dependence lives in w[]).
template<int C>
__device__ __forceinline__ float colval(const float (&xr)[16], const float (&w)[16]) {
  if constexpr (COLS.mode[C] == 3)      return (xr[COLS.a[C]] * xr[COLS.b[C]]) * w[COLS.o[C]];
  else if constexpr (COLS.mode[C] == 2) return xr[COLS.a[C]] * w[COLS.o[C]];
  else if constexpr (COLS.mode[C] == 1) return w[COLS.o[C]];
  else if constexpr (COLS.mode[C] == 4) return 1.0f;
  else                                  return 0.0f;
}

template<int Q>
__device__ __forceinline__ void setw(const float (&xr)[4][16], float (&w)[4][16]) {
  #pragma unroll
  for (int t = 0; t < 4; ++t)
    #pragma unroll
    for (int o = 0; o < 16; ++o)
      w[t][o] = xr[t][(o + Q > 15) ? 15 : (o + Q)];
}

template<int S>
__device__ __forceinline__ void steps(const _Float16* __restrict__ wfq,
                                      const float (&xr)[4][16], const float (&w)[4][16],
                                      float4v (&acc)[4]) {
  if constexpr (S < NSTEP) {
    const half8 bf = *(const half8*)(wfq + S * 512);     // ds_read_b128, imm offset
    #pragma unroll
    for (int t = 0; t < 4; ++t) {
      const f16x2 p01 = __builtin_amdgcn_cvt_pkrtz(colval<S * 8 + 0>(xr[t], w[t]),
                                                   colval<S * 8 + 1>(xr[t], w[t]));
      const f16x2 p23 = __builtin_amdgcn_cvt_pkrtz(colval<S * 8 + 2>(xr[t], w[t]),
                                                   colval<S * 8 + 3>(xr[t], w[t]));
      const f16x2 p45 = __builtin_amdgcn_cvt_pkrtz(colval<S * 8 + 4>(xr[t], w[t]),
                                                   colval<S * 8 + 5>(xr[t], w[t]));
      const f16x2 p67 = __builtin_amdgcn_cvt_pkrtz(colval<S * 8 + 6>(xr[t], w[t]),
                                                   colval<S * 8 + 7>(xr[t], w[t]));
      const f16x4 lo = __builtin_shufflevector(p01, p23, 0, 1, 2, 3);
      const f16x4 hi = __builtin_shufflevector(p45, p67, 0, 1, 2, 3);
      const f16x8 a8 = __builtin_shufflevector(lo, hi, 0, 1, 2, 3, 4, 5, 6, 7);
      const half8 af = __builtin_bit_cast(half8, a8);
      acc[t] = __builtin_amdgcn_mfma_f32_16x16x32_f16(af, bf, acc[t], 0, 0, 0);
    }
    steps<S + 1>(wfq, xr, w, acc);
  }
}

// Block = 256 threads = 4 waves; each wave owns 64 rows (4 m-tiles of 16).
// Lane (m=lane&15, q=lane>>4) computes A[m][k=q*8+j] directly in registers —
// no LDS feature transpose. Only LDS traffic: 39 B-fragment reads per lane.
__global__ __launch_bounds__(256, 2)
void taylor_fwd(const float* __restrict__ X, const _Float16* __restrict__ Wp,
                float* __restrict__ O) {
  __shared__ _Float16 wfrag[NSTEP * 512];          // 39936 B
  const int tid  = threadIdx.x;
  const int lane = tid & 63;
  const int wv   = tid >> 6;
  const int m    = lane & 15;
  const int q    = lane >> 4;

  // stage W fragments (coalesced float4 copy from d_ws)
  {
    float4v* dst = (float4v*)wfrag;
    const float4v* src = (const float4v*)Wp;
    #pragma unroll
    for (int i = 0; i < 10; ++i) {
      const int idx = tid + i * 256;
      if (idx < NSTEP * 64) dst[idx] = src[idx];
    }
  }
  __syncthreads();

  // load 4 rows of x (lanes sharing m load identical rows -> coalesced/broadcast)
  const int rb = blockIdx.x * 256 + wv * 64;
  float xr[4][16];
  #pragma unroll
  for (int t = 0; t < 4; ++t) {
    const float4v* xp = (const float4v*)(X + (size_t)(rb + t * 16 + m) * 16);
    #pragma unroll
    for (int c4 = 0; c4 < 4; ++c4) {
      const float4v v = xp[c4];
      xr[t][c4 * 4 + 0] = v[0]; xr[t][c4 * 4 + 1] = v[1];
      xr[t][c4 * 4 + 2] = v[2]; xr[t][c4 * 4 + 3] = v[3];
    }
  }

  // q-shifted view w[o] = xr[o+q] (clamped), built once under a 4-way branch
  float w[4][16];
  if (q == 0)      setw<0>(xr, w);
  else if (q == 1) setw<1>(xr, w);
  else if (q == 2) setw<2>(xr, w);
  else             setw<3>(xr, w);

  float4v acc[4];
  #pragma unroll
  for (int t = 0; t < 4; ++t) acc[t] = (float4v){0.f, 0.f, 0.f, 0.f};

  const _Float16* wfq = wfrag + (q * 16 + m) * 8;   // + S*512 per step
  steps<0>(wfq, xr, w, acc);

  // Epilogue: C/D layout col = lane&15, row = q*4 + reg
  #pragma unroll
  for (int t = 0; t < 4; ++t) {
    #pragma unroll
    for (int r = 0; r < 4; ++r) {
      const int row = rb + t * 16 + q * 4 + r;
      O[(size_t)row * 16 + m] = acc[t][r];
    }
  }
}

extern "C" void kernel_launch(void* const* d_in, const int* in_sizes, int n_in,
                              void* d_out, int out_size, void* d_ws, size_t ws_size,
                              hipStream_t stream) {
  const float* X = (const float*)d_in[0];
  const float* W = (const float*)d_in[1];
  float*       O = (float*)d_out;
  _Float16*    Wp = (_Float16*)d_ws;               // NSTEP*64*16 B = 39936 B
  const int batch = in_sizes[0] / 16;              // 262144
  const int grid  = batch / 256;                   // 1024 blocks x 256 rows

  build_wfrag<<<(NSTEP * 64 + 255) / 256, 256, 0, stream>>>(W, Wp);
  taylor_fwd<<<grid, 256, 0, stream>>>(X, Wp, O);
}

// Round 5
// 89.944 us; speedup vs baseline: 4.8261x; 1.0066x over previous
//
#include <hip/hip_runtime.h>

#define NSTEP 39                 // K = 39*32 = 1248 slots
#define NCOL  (NSTEP * 8)        // 312 feature columns (8 per K-step), 4 q-slots each

typedef _Float16 half8   __attribute__((ext_vector_type(8)));
typedef __fp16   f16x2   __attribute__((ext_vector_type(2)));
typedef __fp16   f16x4   __attribute__((ext_vector_type(4)));
typedef __fp16   f16x8   __attribute__((ext_vector_type(8)));
typedef float    float4v __attribute__((ext_vector_type(4)));

// Column table. Each column c holds 4 features (q = 0..3), with the
// q-dependent index QUAD-ALIGNED: third factor = x_{o+q}, o in {0,4,8,12}.
//   mode 3: x_a * x_b * x_{o+q}   (valid iff o+q >= a)       [deg-3, i=o+q]
//   mode 2: x_a * x_{o+q}         (valid iff o+q <= a)       [deg-2, b=o+q]
//   mode 1: x_{o+q}               (always valid; +identity)  [deg-1]
//   mode 4: 1.0                   (valid iff q == 0)         [deg-0]
//   mode 0: pad
// Invalid slots are zeroed on the W side; A side computes garbage * 0.
struct Cols { short mode[NCOL]; short a[NCOL]; short b[NCOL]; short o[NCOL]; };
static constexpr Cols mk_cols() {
  Cols c{};
  int k = 0;
  for (int o = 0; o < 16; o += 4) { c.mode[k] = 1; c.o[k] = (short)o; ++k; }   // 4 cols
  c.mode[k] = 4; ++k;                                                          // 1 col
  for (int a = 0; a < 16; ++a)                                                 // 40 cols
    for (int o = 0; o <= a; o += 4) { c.mode[k] = 2; c.a[k] = (short)a; c.o[k] = (short)o; ++k; }
  for (int a = 0; a < 16; ++a)                                                 // 260 cols
    for (int b = 0; b <= a; ++b)
      for (int o = (a & ~3); o < 16; o += 4) {
        c.mode[k] = 3; c.a[k] = (short)a; c.b[k] = (short)b; c.o[k] = (short)o; ++k;
      }
  for (; k < NCOL; ++k) c.mode[k] = 0;                                         // 7 pad cols
  return c;
}
static constexpr Cols COLS = mk_cols();

// ---- Pre-kernel: f16 W fragments (permutation + validity zeroing + identity
// fold) into d_ws. Entry e = (step, q, n): 8 halfs = B[k=step*32+q*8+j][n].
__global__ void build_wfrag(const float* __restrict__ W, _Float16* __restrict__ Wp) {
  const int e = blockIdx.x * 256 + threadIdx.x;
  if (e >= NSTEP * 64) return;
  const int step = e >> 6;
  const int q    = (e >> 4) & 3;
  const int n    = e & 15;
  half8 hv;
  #pragma unroll
  for (int j = 0; j < 8; ++j) {
    const int c = step * 8 + j;
    const int mode = COLS.mode[c], a = COLS.a[c], b = COLS.b[c], o = COLS.o[c];
    float v = 0.0f;
    if (mode == 3) {
      const int i = o + q;                      // i <= 15 guaranteed
      if (i >= a) v = W[(153 + i * (i + 1) * (i + 2) / 6 + a * (a + 1) / 2 + b) * 16 + n];
    } else if (mode == 2) {
      const int bb = o + q;
      if (bb <= a) v = W[(17 + a * (a + 1) / 2 + bb) * 16 + n];
    } else if (mode == 1) {
      const int i = o + q;
      v = W[(1 + i) * 16 + n];
      if (i == n) v += 1.0f;                    // fold residual: out = x + poly@W
    } else if (mode == 4) {
      if (q == 0) v = W[n];
    }
    hv[j] = (_Float16)v;
  }
  *(half8*)(Wp + e * 8) = hv;
}

// Feature value for column C. q-dependence lives in w4[o>>2] = x_{o+q}.
template<int C>
__device__ __forceinline__ float colval(const float (&xr)[16], const float (&w4)[4]) {
  if constexpr (COLS.mode[C] == 3)      return (xr[COLS.a[C]] * xr[COLS.b[C]]) * w4[COLS.o[C] >> 2];
  else if constexpr (COLS.mode[C] == 2) return xr[COLS.a[C]] * w4[COLS.o[C] >> 2];
  else if constexpr (COLS.mode[C] == 1) return w4[COLS.o[C] >> 2];
  else if constexpr (COLS.mode[C] == 4) return 1.0f;
  else                                  return 0.0f;
}

template<int Q>
__device__ __forceinline__ void setw4(const float (&xr)[2][16], float (&w4)[2][4]) {
  #pragma unroll
  for (int t = 0; t < 2; ++t)
    #pragma unroll
    for (int j = 0; j < 4; ++j)
      w4[t][j] = xr[t][4 * j + Q];
}

template<int S>
__device__ __forceinline__ void steps(const _Float16* __restrict__ wfq,
                                      const float (&xr)[2][16], const float (&w4)[2][4],
                                      float4v (&acc)[2]) {
  if constexpr (S < NSTEP) {
    const half8 bf = *(const half8*)(wfq + S * 512);     // ds_read_b128, imm offset
    #pragma unroll
    for (int t = 0; t < 2; ++t) {
      const f16x2 p01 = __builtin_amdgcn_cvt_pkrtz(colval<S * 8 + 0>(xr[t], w4[t]),
                                                   colval<S * 8 + 1>(xr[t], w4[t]));
      const f16x2 p23 = __builtin_amdgcn_cvt_pkrtz(colval<S * 8 + 2>(xr[t], w4[t]),
                                                   colval<S * 8 + 3>(xr[t], w4[t]));
      const f16x2 p45 = __builtin_amdgcn_cvt_pkrtz(colval<S * 8 + 4>(xr[t], w4[t]),
                                                   colval<S * 8 + 5>(xr[t], w4[t]));
      const f16x2 p67 = __builtin_amdgcn_cvt_pkrtz(colval<S * 8 + 6>(xr[t], w4[t]),
                                                   colval<S * 8 + 7>(xr[t], w4[t]));
      const f16x4 lo = __builtin_shufflevector(p01, p23, 0, 1, 2, 3);
      const f16x4 hi = __builtin_shufflevector(p45, p67, 0, 1, 2, 3);
      const f16x8 a8 = __builtin_shufflevector(lo, hi, 0, 1, 2, 3, 4, 5, 6, 7);
      const half8 af = __builtin_bit_cast(half8, a8);
      acc[t] = __builtin_amdgcn_mfma_f32_16x16x32_f16(af, bf, acc[t], 0, 0, 0);
    }
    steps<S + 1>(wfq, xr, w4, acc);
  }
}

// Block = 512 threads = 8 waves; each wave owns 32 rows (2 m-tiles of 16).
// 8192 waves total -> up to 8 waves/SIMD (vs 4 before). Lane (m, q) computes
// A[m][k=q*8+j] directly in registers — only LDS traffic is 39 bf reads.
__global__ __launch_bounds__(512, 6)
void taylor_fwd(const float* __restrict__ X, const _Float16* __restrict__ Wp,
                float* __restrict__ O) {
  __shared__ _Float16 wfrag[NSTEP * 512];          // 39936 B
  const int tid  = threadIdx.x;
  const int lane = tid & 63;
  const int wv   = tid >> 6;
  const int m    = lane & 15;
  const int q    = lane >> 4;

  // stage W fragments (coalesced float4 copy from d_ws)
  {
    float4v* dst = (float4v*)wfrag;
    const float4v* src = (const float4v*)Wp;
    #pragma unroll
    for (int i = 0; i < 5; ++i) {
      const int idx = tid + i * 512;
      if (idx < NSTEP * 64) dst[idx] = src[idx];
    }
  }
  __syncthreads();

  // load 2 rows of x (lanes sharing m load identical rows -> coalesced/broadcast)
  const int rb = blockIdx.x * 256 + wv * 32;
  float xr[2][16];
  #pragma unroll
  for (int t = 0; t < 2; ++t) {
    const float4v* xp = (const float4v*)(X + (size_t)(rb + t * 16 + m) * 16);
    #pragma unroll
    for (int c4 = 0; c4 < 4; ++c4) {
      const float4v v = xp[c4];
      xr[t][c4 * 4 + 0] = v[0]; xr[t][c4 * 4 + 1] = v[1];
      xr[t][c4 * 4 + 2] = v[2]; xr[t][c4 * 4 + 3] = v[3];
    }
  }

  // quad-aligned q-shifted view: w4[j] = x_{4j+q}
  float w4[2][4];
  if (q == 0)      setw4<0>(xr, w4);
  else if (q == 1) setw4<1>(xr, w4);
  else if (q == 2) setw4<2>(xr, w4);
  else             setw4<3>(xr, w4);

  float4v acc[2];
  acc[0] = (float4v){0.f, 0.f, 0.f, 0.f};
  acc[1] = (float4v){0.f, 0.f, 0.f, 0.f};

  const _Float16* wfq = wfrag + (q * 16 + m) * 8;   // + S*512 per step
  steps<0>(wfq, xr, w4, acc);

  // Epilogue: C/D layout col = lane&15, row = q*4 + reg
  #pragma unroll
  for (int t = 0; t < 2; ++t) {
    #pragma unroll
    for (int r = 0; r < 4; ++r) {
      const int row = rb + t * 16 + q * 4 + r;
      O[(size_t)row * 16 + m] = acc[t][r];
    }
  }
}

extern "C" void kernel_launch(void* const* d_in, const int* in_sizes, int n_in,
                              void* d_out, int out_size, void* d_ws, size_t ws_size,
                              hipStream_t stream) {
  const float* X = (const float*)d_in[0];
  const float* W = (const float*)d_in[1];
  float*       O = (float*)d_out;
  _Float16*    Wp = (_Float16*)d_ws;               // NSTEP*64*16 B = 39936 B
  const int batch = in_sizes[0] / 16;              // 262144
  const int grid  = batch / 256;                   // 1024 blocks x 256 rows

  build_wfrag<<<(NSTEP * 64 + 255) / 256, 256, 0, stream>>>(W, Wp);
  taylor_fwd<<<grid, 512, 0, stream>>>(X, Wp, O);
}